// Round 6
// baseline (247.616 us; speedup 1.0000x reference)
//
#include <hip/hip_runtime.h>
#include <math.h>
#include <float.h>

typedef _Float16 half8 __attribute__((ext_vector_type(8)));
typedef float f32x4 __attribute__((ext_vector_type(4)));

namespace {
constexpr int kH = 8192, kE = 256, kTopK = 8, kTok = 8192;
constexpr int kIdxOff = kTok * kTopK;          // 65536
constexpr int kLogitsOff = 2 * kTok * kTopK;   // 131072
constexpr int kBM = 128, kBN = 128, kBK = 32;
constexpr int kPadH = 40;                      // x-tile LDS row stride (halfs)
constexpr int kCand = 16;
constexpr float kEps = 5e-5f;                  // gap-trust margin
constexpr float kInvScale = 1.0f / 262144.0f;  // 2^-18 (x*2^10, W*2^8)
// ws layout in floats: Wt fp32 | Wth fp16(swz) | Wtl fp16(swz) | partials
constexpr size_t kWtF   = (size_t)kE * kH;             // 8MB
constexpr size_t kWtlF  = kWtF + (size_t)kE * kH / 2;  // Wth is 4MB
constexpr size_t kPartF = kWtF + (size_t)kE * kH;      // 16MB offset
constexpr size_t kPartStride = (size_t)kTok * kE;      // 8MB per partial
}

// 16B async global->LDS copy (dest = wave-uniform base + lane*16)
__device__ __forceinline__ void gld16(const _Float16* g, _Float16* l) {
    __builtin_amdgcn_global_load_lds(
        (const __attribute__((address_space(1))) void*)g,
        (__attribute__((address_space(3))) void*)l, 16, 0, 0);
}

// swizzled k-index for Wth/Wtl storage: permute 16B chunks within each 64B group
__device__ __forceinline__ int kswz(int e, int k) {
    return (k & ~31) | (((((k >> 3) & 3) ^ ((e >> 1) & 3))) << 3) | (k & 7);
}

// ---------- Kernel A: W[k][e] -> Wt fp32 [e][k] + swizzled fp16 split --------
__global__ __launch_bounds__(1024)
void prep_w(const float* __restrict__ W, float* __restrict__ Wt,
            _Float16* __restrict__ Wth, _Float16* __restrict__ Wtl) {
    __shared__ float tile[32][33];
    const int k0 = blockIdx.x * 32, e0 = blockIdx.y * 32;
    const int tx = threadIdx.x, ty = threadIdx.y;
    tile[ty][tx] = W[(size_t)(k0 + ty) * kE + (e0 + tx)];
    __syncthreads();
    const float v = tile[tx][ty];
    const int e = e0 + ty, k = k0 + tx;
    Wt[(size_t)e * kH + k] = v;
    const float vs = v * 256.0f;
    const _Float16 h = (_Float16)vs;
    const size_t os = (size_t)e * kH + kswz(e, k);
    Wth[os] = h;
    Wtl[os] = (_Float16)(vs - (float)h);
}

// ---------- Kernel B: fp16x3 MFMA GEMM, async-W staging ----------------------
__global__ __launch_bounds__(256, 2)
void router_gemm_mfma(const float* __restrict__ x,
                      const _Float16* __restrict__ Wth,
                      const _Float16* __restrict__ Wtl,
                      float* __restrict__ p0, float* __restrict__ pws,
                      int kchunk)
{
    __shared__ __align__(16) _Float16 sxh[kBM * kPadH];
    __shared__ __align__(16) _Float16 sxl[kBM * kPadH];
    __shared__ __align__(16) _Float16 swh[kBN * kBK];
    __shared__ __align__(16) _Float16 swl[kBN * kBK];

    const int tid  = threadIdx.x;
    const int lane = tid & 63;
    const int w    = tid >> 6;
    const int wm   = w >> 1, wn = w & 1;
    const int t0   = blockIdx.x * kBM;
    const int e0   = blockIdx.y * kBN;
    const int kbase = blockIdx.z * kchunk;
    const int nsteps = kchunk / kBK;

    f32x4 acc[4][4];
    #pragma unroll
    for (int m = 0; m < 4; ++m)
        #pragma unroll
        for (int n = 0; n < 4; ++n) {
            acc[m][n][0] = 0.f; acc[m][n][1] = 0.f;
            acc[m][n][2] = 0.f; acc[m][n][3] = 0.f;
        }

    // --- W async-staging map: wave w covers row-segments {w, w+4} (16 rows ea)
    const size_t wro0 = (size_t)(e0 + (w << 4) + (lane >> 2)) * kH
                        + kbase + ((lane & 3) << 3);
    const size_t wro1 = wro0 + (size_t)64 * kH;          // segment w+4
    _Float16* lwh0 = swh + (w << 9);
    _Float16* lwh1 = swh + (w << 9) + 2048;
    _Float16* lwl0 = swl + (w << 9);
    _Float16* lwl1 = swl + (w << 9) + 2048;

    // --- x staging map: thread -> row tid>>1, float cols (tid&1)*16 .. +15
    const int srow = tid >> 1;
    const int scg  = (tid & 1) << 4;
    const float* xp = x + (size_t)(t0 + srow) * kH + kbase + scg;

    float4 xv0 = *reinterpret_cast<const float4*>(xp);
    float4 xv1 = *reinterpret_cast<const float4*>(xp + 4);
    float4 xv2 = *reinterpret_cast<const float4*>(xp + 8);
    float4 xv3 = *reinterpret_cast<const float4*>(xp + 12);

    const int fr  = lane & 15;
    const int q   = lane >> 4;
    const int fkA = q << 3;
    const int fkB = ((q ^ ((fr >> 1) & 3)) << 3);   // un-swizzle on read

    for (int t = 0; t < nsteps; ++t) {
        // [A] W buffer free -> issue async W staging for step t
        const size_t ko = (size_t)t << 5;
        gld16(Wth + wro0 + ko, lwh0);
        gld16(Wth + wro1 + ko, lwh1);
        gld16(Wtl + wro0 + ko, lwl0);
        gld16(Wtl + wro1 + ko, lwl1);

        // convert x(t) -> LDS (VALU covers W load latency)
        float xf[16];
        xf[0]=xv0.x; xf[1]=xv0.y; xf[2]=xv0.z; xf[3]=xv0.w;
        xf[4]=xv1.x; xf[5]=xv1.y; xf[6]=xv1.z; xf[7]=xv1.w;
        xf[8]=xv2.x; xf[9]=xv2.y; xf[10]=xv2.z; xf[11]=xv2.w;
        xf[12]=xv3.x; xf[13]=xv3.y; xf[14]=xv3.z; xf[15]=xv3.w;
        half8 h0, h1, l0, l1;
        #pragma unroll
        for (int i = 0; i < 8; ++i) {
            const float sA = xf[i] * 1024.0f;
            const _Float16 hA = (_Float16)sA;
            h0[i] = hA; l0[i] = (_Float16)(sA - (float)hA);
            const float sB = xf[i + 8] * 1024.0f;
            const _Float16 hB = (_Float16)sB;
            h1[i] = hB; l1[i] = (_Float16)(sB - (float)hB);
        }
        *reinterpret_cast<half8*>(&sxh[srow * kPadH + scg])     = h0;
        *reinterpret_cast<half8*>(&sxh[srow * kPadH + scg + 8]) = h1;
        *reinterpret_cast<half8*>(&sxl[srow * kPadH + scg])     = l0;
        *reinterpret_cast<half8*>(&sxl[srow * kPadH + scg + 8]) = l1;

        __syncthreads();   // [B] all staged (vmcnt drained by compiler)

        // issue x(t+1) reg loads under the MFMA phase
        if (t + 1 < nsteps) {
            const float* nx = xp + ((size_t)(t + 1) << 5);
            xv0 = *reinterpret_cast<const float4*>(nx);
            xv1 = *reinterpret_cast<const float4*>(nx + 4);
            xv2 = *reinterpret_cast<const float4*>(nx + 8);
            xv3 = *reinterpret_cast<const float4*>(nx + 12);
        }

        half8 ah[4], al[4];
        #pragma unroll
        for (int m = 0; m < 4; ++m) {
            const int arow = (wm << 6) + (m << 4) + fr;
            ah[m] = *reinterpret_cast<const half8*>(&sxh[arow * kPadH + fkA]);
            al[m] = *reinterpret_cast<const half8*>(&sxl[arow * kPadH + fkA]);
        }
        #pragma unroll
        for (int n = 0; n < 4; ++n) {
            const int brow = (wn << 6) + (n << 4) + fr;
            const half8 bh = *reinterpret_cast<const half8*>(&swh[brow * kBK + fkB]);
            const half8 bl = *reinterpret_cast<const half8*>(&swl[brow * kBK + fkB]);
            #pragma unroll
            for (int m = 0; m < 4; ++m) {
                acc[m][n] = __builtin_amdgcn_mfma_f32_16x16x32_f16(ah[m], bh, acc[m][n], 0, 0, 0);
                acc[m][n] = __builtin_amdgcn_mfma_f32_16x16x32_f16(ah[m], bl, acc[m][n], 0, 0, 0);
                acc[m][n] = __builtin_amdgcn_mfma_f32_16x16x32_f16(al[m], bh, acc[m][n], 0, 0, 0);
            }
        }
        __syncthreads();   // [A'] compute done, buffers reusable
    }

    float* dst = (blockIdx.z == 0) ? p0 : (pws + (size_t)(blockIdx.z - 1) * kPartStride);
    const int r0 = (lane >> 4) << 2;
    const int c0 = lane & 15;
    #pragma unroll
    for (int m = 0; m < 4; ++m)
        #pragma unroll
        for (int n = 0; n < 4; ++n) {
            const int col = e0 + (wn << 6) + (n << 4) + c0;
            #pragma unroll
            for (int r = 0; r < 4; ++r) {
                const int row = t0 + (wm << 6) + (m << 4) + r0 + r;
                dst[(size_t)row * kE + col] = acc[m][n][r] * kInvScale;
            }
        }
}

// ---------- Kernel C: combine + select + (rare) ILP-4 fp64 refine ------------
#define ARGMAX_ROUND(r)                                                        \
    {                                                                          \
        float bv = v0; int bi = (lane << 2);                                   \
        if (v1 > bv) { bv = v1; bi = (lane << 2) + 1; }                        \
        if (v2 > bv) { bv = v2; bi = (lane << 2) + 2; }                        \
        if (v3 > bv) { bv = v3; bi = (lane << 2) + 3; }                        \
        _Pragma("unroll")                                                      \
        for (int off = 32; off > 0; off >>= 1) {                               \
            const float ov = __shfl_xor(bv, off, 64);                          \
            const int   oi = __shfl_xor(bi, off, 64);                          \
            if (ov > bv || (ov == bv && oi < bi)) { bv = ov; bi = oi; }        \
        }                                                                      \
        if (lane == (r)) { myv = bv; myi = bi; }                               \
        if ((bi >> 2) == lane) {                                               \
            const int m = bi & 3;                                              \
            if      (m == 0) v0 = -FLT_MAX;                                    \
            else if (m == 1) v1 = -FLT_MAX;                                    \
            else if (m == 2) v2 = -FLT_MAX;                                    \
            else             v3 = -FLT_MAX;                                    \
        }                                                                      \
    }

__global__ __launch_bounds__(256)
void combine_select(const float* __restrict__ x, const float* __restrict__ Wt,
                    const float* __restrict__ pws, float* __restrict__ out,
                    int npart)
{
    const int lane = threadIdx.x & 63;
    const int w    = threadIdx.x >> 6;
    const int row  = blockIdx.x * 4 + w;
    float* logits = out + kLogitsOff;
    const size_t rb = (size_t)row * kE + (lane << 2);

    float4 s = *reinterpret_cast<const float4*>(logits + rb);
    for (int p = 0; p < npart; ++p) {
        const float4 q = *reinterpret_cast<const float4*>(pws + (size_t)p * kPartStride + rb);
        s.x += q.x; s.y += q.y; s.z += q.z; s.w += q.w;
    }
    *reinterpret_cast<float4*>(logits + rb) = s;

    float v0 = s.x, v1 = s.y, v2 = s.z, v3 = s.w;
    float myv = -FLT_MAX; int myi = -1;

    #pragma unroll
    for (int r = 0; r < 9; ++r) ARGMAX_ROUND(r)

    const float nv = __shfl_down(myv, 1, 64);
    const unsigned long long amb = __ballot(lane < 8 && (myv - nv) < kEps);

    if (amb == 0ull) {
        const float m = __shfl(myv, 0, 64);
        const float e = (lane < kTopK) ? expf(myv - m) : 0.f;
        float t = e;
        #pragma unroll
        for (int off = 1; off < 8; off <<= 1) t += __shfl_xor(t, off, 64);
        if (lane < kTopK) {
            out[(size_t)row * kTopK + lane]           = e / t;
            out[kIdxOff + (size_t)row * kTopK + lane] = (float)myi;
        }
    } else {
        #pragma unroll
        for (int r = 9; r < kCand; ++r) ARGMAX_ROUND(r)

        const float* xr = x + (size_t)row * kH;
        double dv = -1.0e300;
        #pragma unroll 1
        for (int cg = 0; cg < kCand; cg += 4) {
            const int i0 = __shfl(myi, cg + 0, 64);
            const int i1 = __shfl(myi, cg + 1, 64);
            const int i2 = __shfl(myi, cg + 2, 64);
            const int i3 = __shfl(myi, cg + 3, 64);
            const float* w0 = Wt + (size_t)i0 * kH;
            const float* w1 = Wt + (size_t)i1 * kH;
            const float* w2 = Wt + (size_t)i2 * kH;
            const float* w3 = Wt + (size_t)i3 * kH;
            double a0 = 0.0, a1 = 0.0, a2 = 0.0, a3 = 0.0;
            for (int k = (lane << 2); k < kH; k += 256) {
                const float4 xv = *reinterpret_cast<const float4*>(xr + k);
                const float4 q0 = *reinterpret_cast<const float4*>(w0 + k);
                const float4 q1 = *reinterpret_cast<const float4*>(w1 + k);
                const float4 q2 = *reinterpret_cast<const float4*>(w2 + k);
                const float4 q3 = *reinterpret_cast<const float4*>(w3 + k);
                a0 = fma((double)xv.x, (double)q0.x, a0);
                a1 = fma((double)xv.x, (double)q1.x, a1);
                a2 = fma((double)xv.x, (double)q2.x, a2);
                a3 = fma((double)xv.x, (double)q3.x, a3);
                a0 = fma((double)xv.y, (double)q0.y, a0);
                a1 = fma((double)xv.y, (double)q1.y, a1);
                a2 = fma((double)xv.y, (double)q2.y, a2);
                a3 = fma((double)xv.y, (double)q3.y, a3);
                a0 = fma((double)xv.z, (double)q0.z, a0);
                a1 = fma((double)xv.z, (double)q1.z, a1);
                a2 = fma((double)xv.z, (double)q2.z, a2);
                a3 = fma((double)xv.z, (double)q3.z, a3);
                a0 = fma((double)xv.w, (double)q0.w, a0);
                a1 = fma((double)xv.w, (double)q1.w, a1);
                a2 = fma((double)xv.w, (double)q2.w, a2);
                a3 = fma((double)xv.w, (double)q3.w, a3);
            }
            #pragma unroll
            for (int off = 32; off > 0; off >>= 1) {
                a0 += __shfl_xor(a0, off, 64);
                a1 += __shfl_xor(a1, off, 64);
                a2 += __shfl_xor(a2, off, 64);
                a3 += __shfl_xor(a3, off, 64);
            }
            if (lane == cg + 0) dv = a0;
            if (lane == cg + 1) dv = a1;
            if (lane == cg + 2) dv = a2;
            if (lane == cg + 3) dv = a3;
        }

        double cv = dv; int ci = myi;
        double mx = 0.0, ssum = 0.0, keepv = 0.0; int keepi = 0;
        #pragma unroll 1
        for (int r = 0; r < kTopK; ++r) {
            double bv = cv; int bi = ci;
            #pragma unroll
            for (int off = 32; off > 0; off >>= 1) {
                const double ov = __shfl_xor(bv, off, 64);
                const int    oi = __shfl_xor(bi, off, 64);
                if (ov > bv || (ov == bv && oi < bi)) { bv = ov; bi = oi; }
            }
            if (r == 0) mx = bv;
            ssum += exp(bv - mx);
            if (lane == r) { keepv = bv; keepi = bi; }
            if (ci == bi) cv = -1.0e300;
        }
        if (lane < kTopK) {
            out[(size_t)row * kTopK + lane]           = (float)(exp(keepv - mx) / ssum);
            out[kIdxOff + (size_t)row * kTopK + lane] = (float)keepi;
        }
    }
}

extern "C" void kernel_launch(void* const* d_in, const int* in_sizes, int n_in,
                              void* d_out, int out_size, void* d_ws, size_t ws_size,
                              hipStream_t stream) {
    const float* x  = (const float*)d_in[0];
    const float* Wr = (const float*)d_in[1];
    float* out = (float*)d_out;
    float* Wt  = (float*)d_ws;
    _Float16* Wth = (_Float16*)((float*)d_ws + kWtF);
    _Float16* Wtl = (_Float16*)((float*)d_ws + kWtlF);
    float* pws = (float*)d_ws + kPartF;
    (void)in_sizes; (void)n_in; (void)out_size;

    const size_t need8 = (kPartF + 7 * kPartStride) * sizeof(float);  // 72MB
    const int nkc = (ws_size >= need8) ? 8 : 4;
    const int kchunk = kH / nkc;

    hipLaunchKernelGGL(prep_w, dim3(kH / 32, kE / 32), dim3(32, 32), 0, stream,
                       Wr, Wt, Wth, Wtl);
    hipLaunchKernelGGL(router_gemm_mfma, dim3(kTok / kBM, kE / kBN, nkc), dim3(256),
                       0, stream, x, Wth, Wtl, out + kLogitsOff, pws, kchunk);
    hipLaunchKernelGGL(combine_select, dim3(kTok / 4), dim3(256), 0, stream,
                       x, Wt, pws, out, nkc - 1);
}

// Round 7
// 230.292 us; speedup vs baseline: 1.0752x; 1.0752x over previous
//
#include <hip/hip_runtime.h>
#include <math.h>
#include <float.h>

typedef _Float16 half8 __attribute__((ext_vector_type(8)));
typedef float f32x4 __attribute__((ext_vector_type(4)));

namespace {
constexpr int kH = 8192, kE = 256, kTopK = 8, kTok = 8192;
constexpr int kIdxOff = kTok * kTopK;          // 65536
constexpr int kLogitsOff = 2 * kTok * kTopK;   // 131072
constexpr int kBM = 128, kBN = 128, kBK = 32;
constexpr int kPadH = 40;                      // x-tile LDS row stride (halfs)
constexpr int kCand = 16;
constexpr float kEps = 5e-5f;                  // gap-trust margin
constexpr float kInvScale = 1.0f / 262144.0f;  // 2^-18 (x*2^10, W*2^8)
// ws layout in floats: Wt fp32 | Wth fp16 | Wtl fp16 | partials
constexpr size_t kWtF   = (size_t)kE * kH;             // 8MB
constexpr size_t kWtlF  = kWtF + (size_t)kE * kH / 2;  // Wth is 4MB
constexpr size_t kPartF = kWtF + (size_t)kE * kH;      // 16MB offset
constexpr size_t kPartStride = (size_t)kTok * kE;      // 8MB per partial
}

// 16B async global->LDS copy (dest = wave-uniform base + lane*16)
__device__ __forceinline__ void gld16(const _Float16* g, _Float16* l) {
    __builtin_amdgcn_global_load_lds(
        (const __attribute__((address_space(1))) void*)g,
        (__attribute__((address_space(3))) void*)l, 16, 0, 0);
}

// ---------- Kernel A: W[k][e] -> Wt fp32 [e][k] + plain fp16 split ----------
__global__ __launch_bounds__(1024)
void prep_w(const float* __restrict__ W, float* __restrict__ Wt,
            _Float16* __restrict__ Wth, _Float16* __restrict__ Wtl) {
    __shared__ float tile[32][33];
    const int k0 = blockIdx.x * 32, e0 = blockIdx.y * 32;
    const int tx = threadIdx.x, ty = threadIdx.y;
    tile[ty][tx] = W[(size_t)(k0 + ty) * kE + (e0 + tx)];
    __syncthreads();
    const float v = tile[tx][ty];
    const size_t o = (size_t)(e0 + ty) * kH + (k0 + tx);
    Wt[o] = v;
    const float vs = v * 256.0f;
    const _Float16 h = (_Float16)vs;
    Wth[o] = h;
    Wtl[o] = (_Float16)(vs - (float)h);
}

// ---------- Kernel B: fp16x3 MFMA GEMM, single-barrier stage-ahead loop ------
__global__ __launch_bounds__(256, 2)
void router_gemm_mfma(const float* __restrict__ x,
                      const _Float16* __restrict__ Wth,
                      const _Float16* __restrict__ Wtl,
                      float* __restrict__ p0, float* __restrict__ pws,
                      int kchunk)
{
    __shared__ __align__(16) _Float16 sxh[2][kBM * kPadH];
    __shared__ __align__(16) _Float16 sxl[2][kBM * kPadH];
    __shared__ __align__(16) _Float16 swh[2][kBN * kBK];
    __shared__ __align__(16) _Float16 swl[2][kBN * kBK];

    const int tid  = threadIdx.x;
    const int lane = tid & 63;
    const int w    = tid >> 6;
    const int wm   = w >> 1, wn = w & 1;
    const int t0   = blockIdx.x * kBM;
    const int e0   = blockIdx.y * kBN;
    const int kbase = blockIdx.z * kchunk;
    const int nsteps = kchunk / kBK;

    f32x4 acc[4][4];
    #pragma unroll
    for (int m = 0; m < 4; ++m)
        #pragma unroll
        for (int n = 0; n < 4; ++n) {
            acc[m][n][0] = 0.f; acc[m][n][1] = 0.f;
            acc[m][n][2] = 0.f; acc[m][n][3] = 0.f;
        }

    // --- W async-staging: wave w covers row-segments {w*16, 64+w*16}
    const size_t wro0 = (size_t)(e0 + (w << 4) + (lane >> 2)) * kH
                        + kbase + ((lane & 3) << 3);
    const size_t wro1 = wro0 + (size_t)64 * kH;
    const int wl0 = (w << 9);          // LDS half-offset of wave's segment 0
    const int wl1 = (w << 9) + 2048;   // segment 1

    // --- x staging: thread -> row tid>>1, 16-float group (tid&1)*16
    const int srow = tid >> 1;
    const int scg  = (tid & 1) << 4;
    const float* xp = x + (size_t)(t0 + srow) * kH + kbase + scg;

    float4 xr0, xr1, xr2, xr3;   // holds x(t+1) during step t

#define CVT_STORE(B)                                                           \
    {                                                                          \
        float xf[16];                                                          \
        xf[0]=xr0.x; xf[1]=xr0.y; xf[2]=xr0.z; xf[3]=xr0.w;                    \
        xf[4]=xr1.x; xf[5]=xr1.y; xf[6]=xr1.z; xf[7]=xr1.w;                    \
        xf[8]=xr2.x; xf[9]=xr2.y; xf[10]=xr2.z; xf[11]=xr2.w;                  \
        xf[12]=xr3.x; xf[13]=xr3.y; xf[14]=xr3.z; xf[15]=xr3.w;                \
        half8 h0, h1, l0, l1;                                                  \
        _Pragma("unroll")                                                      \
        for (int i = 0; i < 8; ++i) {                                          \
            const float sA = xf[i] * 1024.0f;                                  \
            const _Float16 hA = (_Float16)sA;                                  \
            h0[i] = hA; l0[i] = (_Float16)(sA - (float)hA);                    \
            const float sB = xf[i + 8] * 1024.0f;                              \
            const _Float16 hB = (_Float16)sB;                                  \
            h1[i] = hB; l1[i] = (_Float16)(sB - (float)hB);                    \
        }                                                                      \
        *reinterpret_cast<half8*>(&sxh[B][srow * kPadH + scg])     = h0;       \
        *reinterpret_cast<half8*>(&sxh[B][srow * kPadH + scg + 8]) = h1;       \
        *reinterpret_cast<half8*>(&sxl[B][srow * kPadH + scg])     = l0;       \
        *reinterpret_cast<half8*>(&sxl[B][srow * kPadH + scg + 8]) = l1;       \
    }

    // ---- prologue: stage buffer 0 (step 0), then preload x(1) ----
    gld16(Wth + wro0, &swh[0][wl0]);
    gld16(Wth + wro1, &swh[0][wl1]);
    gld16(Wtl + wro0, &swl[0][wl0]);
    gld16(Wtl + wro1, &swl[0][wl1]);
    xr0 = *reinterpret_cast<const float4*>(xp);
    xr1 = *reinterpret_cast<const float4*>(xp + 4);
    xr2 = *reinterpret_cast<const float4*>(xp + 8);
    xr3 = *reinterpret_cast<const float4*>(xp + 12);
    CVT_STORE(0)
    if (nsteps > 1) {
        xr0 = *reinterpret_cast<const float4*>(xp + 32);
        xr1 = *reinterpret_cast<const float4*>(xp + 36);
        xr2 = *reinterpret_cast<const float4*>(xp + 40);
        xr3 = *reinterpret_cast<const float4*>(xp + 44);
    }
    __syncthreads();   // drains gld16s + ds_writes: buffer 0 ready

    const int fr = lane & 15;
    const int fk = (lane >> 4) << 3;   // frag k offset (halfs)

    for (int t = 0; t < nsteps; ++t) {
        const int cur = t & 1, nxt = cur ^ 1;

        // ---- stage t+1 (lands at this step's ending barrier) ----
        if (t + 1 < nsteps) {
            const size_t ko = (size_t)(t + 1) << 5;
            gld16(Wth + wro0 + ko, &swh[nxt][wl0]);
            gld16(Wth + wro1 + ko, &swh[nxt][wl1]);
            gld16(Wtl + wro0 + ko, &swl[nxt][wl0]);
            gld16(Wtl + wro1 + ko, &swl[nxt][wl1]);
            CVT_STORE(nxt)                       // x(t+1) -> LDS nxt
            if (t + 2 < nsteps) {                // issue x(t+2) reg loads
                const float* nx = xp + ((size_t)(t + 2) << 5);
                xr0 = *reinterpret_cast<const float4*>(nx);
                xr1 = *reinterpret_cast<const float4*>(nx + 4);
                xr2 = *reinterpret_cast<const float4*>(nx + 8);
                xr3 = *reinterpret_cast<const float4*>(nx + 12);
            }
        }

        // ---- compute step t from buffer cur ----
        half8 ah[4], al[4];
        #pragma unroll
        for (int m = 0; m < 4; ++m) {
            const int arow = (wm << 6) + (m << 4) + fr;
            ah[m] = *reinterpret_cast<const half8*>(&sxh[cur][arow * kPadH + fk]);
            al[m] = *reinterpret_cast<const half8*>(&sxl[cur][arow * kPadH + fk]);
        }
        #pragma unroll
        for (int n = 0; n < 4; ++n) {
            const int brow = (wn << 6) + (n << 4) + fr;
            const half8 bh = *reinterpret_cast<const half8*>(&swh[cur][brow * kBK + fk]);
            const half8 bl = *reinterpret_cast<const half8*>(&swl[cur][brow * kBK + fk]);
            #pragma unroll
            for (int m = 0; m < 4; ++m) {
                acc[m][n] = __builtin_amdgcn_mfma_f32_16x16x32_f16(ah[m], bh, acc[m][n], 0, 0, 0);
                acc[m][n] = __builtin_amdgcn_mfma_f32_16x16x32_f16(ah[m], bl, acc[m][n], 0, 0, 0);
                acc[m][n] = __builtin_amdgcn_mfma_f32_16x16x32_f16(al[m], bh, acc[m][n], 0, 0, 0);
            }
        }

        __syncthreads();   // single barrier: reads(cur) done; staging(nxt) landed
    }
#undef CVT_STORE

    float* dst = (blockIdx.z == 0) ? p0 : (pws + (size_t)(blockIdx.z - 1) * kPartStride);
    const int r0 = (lane >> 4) << 2;
    const int c0 = lane & 15;
    #pragma unroll
    for (int m = 0; m < 4; ++m)
        #pragma unroll
        for (int n = 0; n < 4; ++n) {
            const int col = e0 + (wn << 6) + (n << 4) + c0;
            #pragma unroll
            for (int r = 0; r < 4; ++r) {
                const int row = t0 + (wm << 6) + (m << 4) + r0 + r;
                dst[(size_t)row * kE + col] = acc[m][n][r] * kInvScale;
            }
        }
}

// ---------- Kernel C: combine + select + (rare) ILP-4 fp64 refine ------------
#define ARGMAX_ROUND(r)                                                        \
    {                                                                          \
        float bv = v0; int bi = (lane << 2);                                   \
        if (v1 > bv) { bv = v1; bi = (lane << 2) + 1; }                        \
        if (v2 > bv) { bv = v2; bi = (lane << 2) + 2; }                        \
        if (v3 > bv) { bv = v3; bi = (lane << 2) + 3; }                        \
        _Pragma("unroll")                                                      \
        for (int off = 32; off > 0; off >>= 1) {                               \
            const float ov = __shfl_xor(bv, off, 64);                          \
            const int   oi = __shfl_xor(bi, off, 64);                          \
            if (ov > bv || (ov == bv && oi < bi)) { bv = ov; bi = oi; }        \
        }                                                                      \
        if (lane == (r)) { myv = bv; myi = bi; }                               \
        if ((bi >> 2) == lane) {                                               \
            const int m = bi & 3;                                              \
            if      (m == 0) v0 = -FLT_MAX;                                    \
            else if (m == 1) v1 = -FLT_MAX;                                    \
            else if (m == 2) v2 = -FLT_MAX;                                    \
            else             v3 = -FLT_MAX;                                    \
        }                                                                      \
    }

__global__ __launch_bounds__(256)
void combine_select(const float* __restrict__ x, const float* __restrict__ Wt,
                    const float* __restrict__ pws, float* __restrict__ out,
                    int npart)
{
    const int lane = threadIdx.x & 63;
    const int w    = threadIdx.x >> 6;
    const int row  = blockIdx.x * 4 + w;
    float* logits = out + kLogitsOff;
    const size_t rb = (size_t)row * kE + (lane << 2);

    float4 s = *reinterpret_cast<const float4*>(logits + rb);
    for (int p = 0; p < npart; ++p) {
        const float4 q = *reinterpret_cast<const float4*>(pws + (size_t)p * kPartStride + rb);
        s.x += q.x; s.y += q.y; s.z += q.z; s.w += q.w;
    }
    *reinterpret_cast<float4*>(logits + rb) = s;

    float v0 = s.x, v1 = s.y, v2 = s.z, v3 = s.w;
    float myv = -FLT_MAX; int myi = -1;

    #pragma unroll
    for (int r = 0; r < 9; ++r) ARGMAX_ROUND(r)

    const float nv = __shfl_down(myv, 1, 64);
    const unsigned long long amb = __ballot(lane < 8 && (myv - nv) < kEps);

    if (amb == 0ull) {
        const float m = __shfl(myv, 0, 64);
        const float e = (lane < kTopK) ? expf(myv - m) : 0.f;
        float t = e;
        #pragma unroll
        for (int off = 1; off < 8; off <<= 1) t += __shfl_xor(t, off, 64);
        if (lane < kTopK) {
            out[(size_t)row * kTopK + lane]           = e / t;
            out[kIdxOff + (size_t)row * kTopK + lane] = (float)myi;
        }
    } else {
        #pragma unroll
        for (int r = 9; r < kCand; ++r) ARGMAX_ROUND(r)

        const float* xr = x + (size_t)row * kH;
        double dv = -1.0e300;
        #pragma unroll 1
        for (int cg = 0; cg < kCand; cg += 4) {
            const int i0 = __shfl(myi, cg + 0, 64);
            const int i1 = __shfl(myi, cg + 1, 64);
            const int i2 = __shfl(myi, cg + 2, 64);
            const int i3 = __shfl(myi, cg + 3, 64);
            const float* w0 = Wt + (size_t)i0 * kH;
            const float* w1 = Wt + (size_t)i1 * kH;
            const float* w2 = Wt + (size_t)i2 * kH;
            const float* w3 = Wt + (size_t)i3 * kH;
            double a0 = 0.0, a1 = 0.0, a2 = 0.0, a3 = 0.0;
            for (int k = (lane << 2); k < kH; k += 256) {
                const float4 xv = *reinterpret_cast<const float4*>(xr + k);
                const float4 q0 = *reinterpret_cast<const float4*>(w0 + k);
                const float4 q1 = *reinterpret_cast<const float4*>(w1 + k);
                const float4 q2 = *reinterpret_cast<const float4*>(w2 + k);
                const float4 q3 = *reinterpret_cast<const float4*>(w3 + k);
                a0 = fma((double)xv.x, (double)q0.x, a0);
                a1 = fma((double)xv.x, (double)q1.x, a1);
                a2 = fma((double)xv.x, (double)q2.x, a2);
                a3 = fma((double)xv.x, (double)q3.x, a3);
                a0 = fma((double)xv.y, (double)q0.y, a0);
                a1 = fma((double)xv.y, (double)q1.y, a1);
                a2 = fma((double)xv.y, (double)q2.y, a2);
                a3 = fma((double)xv.y, (double)q3.y, a3);
                a0 = fma((double)xv.z, (double)q0.z, a0);
                a1 = fma((double)xv.z, (double)q1.z, a1);
                a2 = fma((double)xv.z, (double)q2.z, a2);
                a3 = fma((double)xv.z, (double)q3.z, a3);
                a0 = fma((double)xv.w, (double)q0.w, a0);
                a1 = fma((double)xv.w, (double)q1.w, a1);
                a2 = fma((double)xv.w, (double)q2.w, a2);
                a3 = fma((double)xv.w, (double)q3.w, a3);
            }
            #pragma unroll
            for (int off = 32; off > 0; off >>= 1) {
                a0 += __shfl_xor(a0, off, 64);
                a1 += __shfl_xor(a1, off, 64);
                a2 += __shfl_xor(a2, off, 64);
                a3 += __shfl_xor(a3, off, 64);
            }
            if (lane == cg + 0) dv = a0;
            if (lane == cg + 1) dv = a1;
            if (lane == cg + 2) dv = a2;
            if (lane == cg + 3) dv = a3;
        }

        double cv = dv; int ci = myi;
        double mx = 0.0, ssum = 0.0, keepv = 0.0; int keepi = 0;
        #pragma unroll 1
        for (int r = 0; r < kTopK; ++r) {
            double bv = cv; int bi = ci;
            #pragma unroll
            for (int off = 32; off > 0; off >>= 1) {
                const double ov = __shfl_xor(bv, off, 64);
                const int    oi = __shfl_xor(bi, off, 64);
                if (ov > bv || (ov == bv && oi < bi)) { bv = ov; bi = oi; }
            }
            if (r == 0) mx = bv;
            ssum += exp(bv - mx);
            if (lane == r) { keepv = bv; keepi = bi; }
            if (ci == bi) cv = -1.0e300;
        }
        if (lane < kTopK) {
            out[(size_t)row * kTopK + lane]           = (float)(exp(keepv - mx) / ssum);
            out[kIdxOff + (size_t)row * kTopK + lane] = (float)keepi;
        }
    }
}

extern "C" void kernel_launch(void* const* d_in, const int* in_sizes, int n_in,
                              void* d_out, int out_size, void* d_ws, size_t ws_size,
                              hipStream_t stream) {
    const float* x  = (const float*)d_in[0];
    const float* Wr = (const float*)d_in[1];
    float* out = (float*)d_out;
    float* Wt  = (float*)d_ws;
    _Float16* Wth = (_Float16*)((float*)d_ws + kWtF);
    _Float16* Wtl = (_Float16*)((float*)d_ws + kWtlF);
    float* pws = (float*)d_ws + kPartF;
    (void)in_sizes; (void)n_in; (void)out_size;

    const size_t need4 = (kPartF + 3 * kPartStride) * sizeof(float);  // 40MB
    const int nkc = (ws_size >= need4) ? 4 : 2;
    const int kchunk = kH / nkc;

    hipLaunchKernelGGL(prep_w, dim3(kH / 32, kE / 32), dim3(32, 32), 0, stream,
                       Wr, Wt, Wth, Wtl);
    hipLaunchKernelGGL(router_gemm_mfma, dim3(kTok / kBM, kE / kBN, nkc), dim3(256),
                       0, stream, x, Wth, Wtl, out + kLogitsOff, pws, kchunk);
    hipLaunchKernelGGL(combine_select, dim3(kTok / 4), dim3(256), 0, stream,
                       x, Wt, pws, out, nkc - 1);
}